// Round 15
// baseline (928.562 us; speedup 1.0000x reference)
//
#include <hip/hip_runtime.h>

#define K256 __launch_bounds__(256)

constexpr int B = 128;
constexpr int NM = 100000, EM = 400000;
constexpr int NP = 200000, EP = 3200000;
constexpr int DM = 78, DPK = 54, DP2 = 108;
constexpr int XH = 32;   // pro bf16 row stride in ushort2 (128 B)
constexpr int XH4 = 16;  // pro row stride in ushort4
constexpr int MH = 48;   // mol bf16 row stride in ushort2 (192 B, 3 lines)

// ---- bf16 helpers (RTNE) ----
__device__ __forceinline__ float b2f(unsigned short u) {
  return __uint_as_float((unsigned int)u << 16);
}
__device__ __forceinline__ unsigned short f2b(float f) {
  unsigned int b = __float_as_uint(f);
  return (unsigned short)((b + 0x7fffu + ((b >> 16) & 1u)) >> 16);
}

// ---------- CSR build: bucket histogram (LDS-aggregated, no per-node atomics) ----------
template <int SH>
__global__ void K256 k_bhist(const int* __restrict__ dst, int* __restrict__ bhist, int E) {
  __shared__ int lh[512];
  int tid = threadIdx.x;
  for (int t = tid; t < 512; t += 256) lh[t] = 0;
  __syncthreads();
  int c0 = blockIdx.x * 4096;
#pragma unroll
  for (int k = 0; k < 16; k++) {
    int e = c0 + k * 256 + tid;
    if (e < E) atomicAdd(&lh[dst[e] >> SH], 1);
  }
  __syncthreads();
  for (int t = tid; t < 512; t += 256) {
    int c = lh[t];
    if (c) atomicAdd(&bhist[t], c);
  }
}

// one-block scan of bucket counts -> bed (exclusive, +total) and bcur
__global__ void k_scanb(const int* __restrict__ bhist, int* __restrict__ bed,
                        int* __restrict__ bcur, int NB, int E) {
  __shared__ int s[512];
  int tid = threadIdx.x;
  int v = (tid < NB) ? bhist[tid] : 0;
  s[tid] = v;
  __syncthreads();
  for (int off = 1; off < 512; off <<= 1) {
    int t = (tid >= off) ? s[tid - off] : 0;
    __syncthreads();
    s[tid] += t;
    __syncthreads();
  }
  int excl = s[tid] - v;
  if (tid < NB) {
    bed[tid] = excl;
    bcur[tid] = excl;
  }
  if (tid == NB - 1) bed[NB] = E;
}

// Pass A: bucket-grouped edge binning (counting-sort per 4096-edge chunk).
template <int SH>
__global__ void K256 k_bin(const int* __restrict__ src, const int* __restrict__ dst,
                           int* __restrict__ bcur, int2* __restrict__ binned, int E) {
  __shared__ int lh[512];
  __shared__ int gbase[512];
  int c0 = blockIdx.x * 4096;
  int tid = threadIdx.x;
  for (int t = tid; t < 512; t += 256) lh[t] = 0;
  __syncthreads();
  int r[16], dcache[16];
#pragma unroll
  for (int k = 0; k < 16; k++) {
    int e = c0 + k * 256 + tid;
    if (e < E) {
      int d = dst[e];
      dcache[k] = d;
      r[k] = atomicAdd(&lh[d >> SH], 1);
    }
  }
  __syncthreads();
  for (int b = tid; b < 512; b += 256) {
    int c = lh[b];
    gbase[b] = c ? atomicAdd(&bcur[b], c) : 0;
  }
  __syncthreads();
#pragma unroll
  for (int k = 0; k < 16; k++) {
    int e = c0 + k * 256 + tid;
    if (e < E) {
      int d = dcache[k];
      binned[gbase[d >> SH] + r[k]] = make_int2(src[e], d);
    }
  }
}

// Pass B (fused): per-bucket count -> LDS scan -> deg/starts write -> CSR fill.
template <int SH>
__global__ void K256 k_build(const int2* __restrict__ binned, const int* __restrict__ bed,
                             int* __restrict__ deg, int* __restrict__ starts,
                             int* __restrict__ csr, int N) {
  constexpr int NN = 1 << SH;
  constexpr int P = NN / 256;
  __shared__ int lcnt[NN];
  __shared__ int lpair[256];
  int b = blockIdx.x, base = b << SH, tid = threadIdx.x;
  int nn = min(N - base, NN);
  for (int t = tid; t < NN; t += 256) lcnt[t] = 0;
  __syncthreads();
  int e0 = bed[b], e1 = bed[b + 1];
  for (int e = e0 + tid; e < e1; e += 256) atomicAdd(&lcnt[binned[e].y - base], 1);
  __syncthreads();
  int loc[P];
  int psum = 0;
#pragma unroll
  for (int p = 0; p < P; p++) {
    loc[p] = lcnt[tid * P + p];
    psum += loc[p];
  }
  lpair[tid] = psum;
  __syncthreads();
  for (int off = 1; off < 256; off <<= 1) {
    int t = (tid >= off) ? lpair[tid - off] : 0;
    __syncthreads();
    lpair[tid] += t;
    __syncthreads();
  }
  int run = lpair[tid] - psum;
  __syncthreads();  // done reading lcnt as counts; reuse as cursors
#pragma unroll
  for (int p = 0; p < P; p++) {
    int i = tid * P + p;
    int st = e0 + run;
    if (i < nn) {
      deg[base + i] = loc[p];
      starts[base + i] = st;
    }
    lcnt[i] = st;
    run += loc[p];
  }
  __syncthreads();
  for (int e = e0 + tid; e < e1; e += 256) {
    int2 sd = binned[e];
    int p = atomicAdd(&lcnt[sd.y - base], 1);
    csr[p] = sd.x;
  }
}

// ---------- batch segment starts (batch is sorted) ----------
__global__ void K256 k_bstart(const int* __restrict__ batch, int* __restrict__ bstart, int N) {
  int i = blockIdx.x * 256 + threadIdx.x;
  if (i < N) {
    int b = batch[i];
    int pb = (i == 0) ? -1 : batch[i - 1];
    for (int bb = pb + 1; bb <= b; bb++) bstart[bb] = i;
    if (i == N - 1)
      for (int bb = b + 1; bb <= B; bb++) bstart[bb] = N;
  }
}

__global__ void k_inv(const int* __restrict__ bstart, float* __restrict__ inv) {
  int b = threadIdx.x;
  if (b < B) inv[b] = 1.f / fmaxf((float)(bstart[b + 1] - bstart[b]), 1.f);
}

// ---------- tiled transpose ----------
__global__ void K256 k_transT(const float* __restrict__ in, float* __restrict__ out, int R,
                              int C) {
  __shared__ float t[32][33];
  int cb = blockIdx.x * 32, rb = blockIdx.y * 32;
  int tx = threadIdx.x & 31, ty = threadIdx.x >> 5;
  for (int i = ty; i < 32; i += 8) {
    int r = rb + i, c = cb + tx;
    if (r < R && c < C) t[i][tx] = in[(size_t)r * C + c];
  }
  __syncthreads();
  for (int i = ty; i < 32; i += 8) {
    int c = cb + i, r = rb + tx;
    if (r < R && c < C) out[(size_t)c * R + r] = t[tx][i];
  }
}

// ---------- weight prep: cat-form transposed weights ----------
__global__ void K256 k_prepw(const float* __restrict__ c1Wl, const float* __restrict__ c1Wr,
                             const float* __restrict__ c1bl, const float* __restrict__ c2Wl,
                             const float* __restrict__ c2Wr, float* __restrict__ w1cat,
                             float* __restrict__ bl1c, float* __restrict__ w2cat) {
  int i = blockIdx.x * 256 + threadIdx.x;
  if (i < 108 * 56) {
    int k = i / 56, o = i - k * 56;
    w1cat[i] = (o < 54) ? ((k < 54) ? c1Wl[o * 54 + k] : c1Wr[o * 54 + (k - 54)]) : 0.f;
  }
  if (i < 108 * 108) {
    int k = i / 108, o = i - k * 108;
    w2cat[i] = (k < 54) ? c2Wl[o * 54 + k] : c2Wr[o * 54 + (k - 54)];
  }
  if (i < 56) bl1c[i] = (i < 54) ? c1bl[i] : 0.f;
}

// ---------- cast f32 rows -> bf16 rows ----------
template <int DF2, int XHD>
__global__ void K256 k_castg(const float* __restrict__ x, int sstride,
                             ushort2* __restrict__ xh, int N) {
  int t = blockIdx.x * 256 + threadIdx.x;
  if (t < N * DF2) {
    int n = t / DF2, j = t - n * DF2;
    float2 v = *(const float2*)(x + (size_t)n * sstride + 2 * j);
    xh[(size_t)n * XHD + j] = make_ushort2(f2b(v.x), f2b(v.y));
  }
}

// ---------- pro bf16 gather: 4 edges/wave, ushort4 lanes (14 of 16), 8-deep ILP ----------
__global__ void K256 k_gatherh(const ushort4* __restrict__ xh4, const int* __restrict__ starts,
                               const int* __restrict__ deg, const int* __restrict__ csr,
                               ushort4* __restrict__ outh4, int N) {
  int wid = (blockIdx.x * 256 + threadIdx.x) >> 6;
  int lane = threadIdx.x & 63;
  if (wid >= N) return;
  int s = starts[wid], d = deg[wid];
  const int* cp = csr + s;
  int quarter = lane >> 4, sl = lane & 15;
  bool act = sl < 14;
  float a0 = 0.f, a1 = 0.f, a2 = 0.f, a3 = 0.f;
  float b0 = 0.f, b1 = 0.f, b2 = 0.f, b3 = 0.f;
  int j = 0;
  for (; j + 8 <= d; j += 8) {
    if (act) {
      ushort4 v = xh4[(size_t)cp[j + quarter] * XH4 + sl];
      ushort4 w = xh4[(size_t)cp[j + 4 + quarter] * XH4 + sl];
      a0 += b2f(v.x);
      a1 += b2f(v.y);
      a2 += b2f(v.z);
      a3 += b2f(v.w);
      b0 += b2f(w.x);
      b1 += b2f(w.y);
      b2 += b2f(w.z);
      b3 += b2f(w.w);
    }
  }
  for (; j + 4 <= d; j += 4) {
    if (act) {
      ushort4 v = xh4[(size_t)cp[j + quarter] * XH4 + sl];
      a0 += b2f(v.x);
      a1 += b2f(v.y);
      a2 += b2f(v.z);
      a3 += b2f(v.w);
    }
  }
  int r = d - j;
  if (quarter < r && act) {
    ushort4 v = xh4[(size_t)cp[j + quarter] * XH4 + sl];
    a0 += b2f(v.x);
    a1 += b2f(v.y);
    a2 += b2f(v.z);
    a3 += b2f(v.w);
  }
  a0 += b0;
  a1 += b1;
  a2 += b2;
  a3 += b3;
  a0 += __shfl_xor(a0, 16, 64);
  a1 += __shfl_xor(a1, 16, 64);
  a2 += __shfl_xor(a2, 16, 64);
  a3 += __shfl_xor(a3, 16, 64);
  a0 += __shfl_xor(a0, 32, 64);
  a1 += __shfl_xor(a1, 32, 64);
  a2 += __shfl_xor(a2, 32, 64);
  a3 += __shfl_xor(a3, 32, 64);
  if (lane < 14) {
    float inv = 1.f / fmaxf((float)d, 1.f);
    outh4[(size_t)wid * XH4 + lane] =
        make_ushort4(f2b(a0 * inv), f2b(a1 * inv), f2b(a2 * inv), f2b(a3 * inv));
  }
}

// ---------- mol bf16 gather (sum): wave per node, 39 ushort2 lanes, 4-deep ILP ----------
__global__ void K256 k_gatherm(const ushort2* __restrict__ xh, const int* __restrict__ starts,
                               const int* __restrict__ deg, const int* __restrict__ csr,
                               ushort2* __restrict__ outh, int N) {
  int wid = (blockIdx.x * 256 + threadIdx.x) >> 6;
  int lane = threadIdx.x & 63;
  if (wid >= N) return;
  int s = starts[wid], d = deg[wid];
  const int* cp = csr + s;
  bool act = lane < 39;
  float ax = 0.f, ay = 0.f, bx = 0.f, by = 0.f;
  int j = 0;
  for (; j + 4 <= d; j += 4) {
    if (act) {
      ushort2 v0 = xh[(size_t)cp[j] * MH + lane];
      ushort2 v1 = xh[(size_t)cp[j + 1] * MH + lane];
      ushort2 v2 = xh[(size_t)cp[j + 2] * MH + lane];
      ushort2 v3 = xh[(size_t)cp[j + 3] * MH + lane];
      ax += b2f(v0.x) + b2f(v2.x);
      ay += b2f(v0.y) + b2f(v2.y);
      bx += b2f(v1.x) + b2f(v3.x);
      by += b2f(v1.y) + b2f(v3.y);
    }
  }
  for (; j < d; j++) {
    if (act) {
      ushort2 v = xh[(size_t)cp[j] * MH + lane];
      ax += b2f(v.x);
      ay += b2f(v.y);
    }
  }
  ax += bx;
  ay += by;
  if (act) outh[(size_t)wid * MH + lane] = make_ushort2(f2b(ax), f2b(ay));
}

// ---------- mol segmented pooling over bf16 rows, split + ILP-4 ----------
template <int SPLIT>
__global__ void K256 k_pool_segh(const ushort2* __restrict__ xh, const int* __restrict__ bstart,
                                 float* __restrict__ pooled, float coef) {
  constexpr int NPB = 6;  // 39 u2 * 6 = 234 threads
  __shared__ float sp[NPB * DM];
  int b = blockIdx.x / SPLIT;
  int sidx = blockIdx.x - b * SPLIT;
  int tid = threadIdx.x;
  int r0 = bstart[b], r1 = bstart[b + 1];
  int len = r1 - r0;
  int per = (len + SPLIT - 1) / SPLIT;
  int s0 = r0 + sidx * per;
  int s1 = min(r1, s0 + per);
  if (tid < 39 * NPB) {
    int ioff = tid / 39, j = tid - ioff * 39;
    float a0x = 0.f, a0y = 0.f, a1x = 0.f, a1y = 0.f;
    int i = s0 + ioff;
    for (; i + 3 * NPB < s1; i += 4 * NPB) {
      ushort2 v0 = xh[(size_t)i * MH + j];
      ushort2 v1 = xh[(size_t)(i + NPB) * MH + j];
      ushort2 v2 = xh[(size_t)(i + 2 * NPB) * MH + j];
      ushort2 v3 = xh[(size_t)(i + 3 * NPB) * MH + j];
      a0x += b2f(v0.x) + b2f(v2.x);
      a0y += b2f(v0.y) + b2f(v2.y);
      a1x += b2f(v1.x) + b2f(v3.x);
      a1y += b2f(v1.y) + b2f(v3.y);
    }
    for (; i < s1; i += NPB) {
      ushort2 v = xh[(size_t)i * MH + j];
      a0x += b2f(v.x);
      a0y += b2f(v.y);
    }
    sp[ioff * DM + 2 * j] = a0x + a1x;
    sp[ioff * DM + 2 * j + 1] = a0y + a1y;
  }
  __syncthreads();
  if (tid < DM) {
    float s = 0.f;
#pragma unroll
    for (int g = 0; g < NPB; g++) s += sp[g * DM + tid];
    s *= coef;
    if (s != 0.f) atomicAdd(&pooled[b * DM + tid], s);
  }
}

// ---------- SAGE conv1 cat-form: 64-node tile, 4 waves x 14 outputs; bf16 agg in, bf16 out ----------
__global__ void __launch_bounds__(256, 4) k_sage1c(
    const float* __restrict__ x, const ushort2* __restrict__ aggh,
    const float* __restrict__ wcat, const float* __restrict__ blc,
    ushort2* __restrict__ outh, int N) {
  __shared__ float scat[64 * 109];
  int base = blockIdx.x * 64;
  int nn = min(N - base, 64);
  int tid = threadIdx.x;
  for (int t = tid; t < nn * 27; t += 256) {
    int n = t / 27, j = t - n * 27;
    ushort2 va = aggh[(size_t)(base + n) * XH + j];
    float2 vx = *(const float2*)(x + (size_t)(base + n) * 54 + 2 * j);
    float* sr = scat + n * 109;
    sr[2 * j] = b2f(va.x);
    sr[2 * j + 1] = b2f(va.y);
    sr[54 + 2 * j] = vx.x;
    sr[54 + 2 * j + 1] = vx.y;
  }
  __syncthreads();
  int w = tid >> 6, lane = tid & 63;
  int obase = __builtin_amdgcn_readfirstlane(w * 14);
  if (lane >= nn) return;
  float acc[14];
#pragma unroll
  for (int o = 0; o < 14; o++) acc[o] = blc[obase + o];
  const float* rs = scat + lane * 109;
#pragma unroll 2
  for (int k = 0; k < 108; k++) {
    float v = rs[k];
    const float* wr = wcat + k * 56 + obase;
#pragma unroll
    for (int o = 0; o < 14; o++) acc[o] += v * wr[o];
  }
  ushort2* op = outh + (size_t)(base + lane) * XH + (obase >> 1);
#pragma unroll
  for (int o = 0; o < 7; o++)
    op[o] = make_ushort2(f2b(fmaxf(acc[2 * o], 0.f)), f2b(fmaxf(acc[2 * o + 1], 0.f)));
}

// ---------- conv2 + pool cat-form: 64-node tile, 4 waves x 27 outputs; bf16 inputs ----------
template <int SPLIT>
__global__ void __launch_bounds__(256, 4) k_sage2c(
    const ushort2* __restrict__ xt1h, const ushort2* __restrict__ aggh,
    const float* __restrict__ wcat, const float* __restrict__ bl,
    const int* __restrict__ bstart, float* __restrict__ pooled) {
  __shared__ float scat[64 * 109];
  int b = blockIdx.x / SPLIT;
  int sidx = blockIdx.x - b * SPLIT;
  int tid = threadIdx.x;
  int w = tid >> 6, lane = tid & 63;
  int obase = __builtin_amdgcn_readfirstlane(w * 27);
  int r0 = bstart[b], r1 = bstart[b + 1];
  int len = r1 - r0;
  int per = (len + SPLIT - 1) / SPLIT;
  int s0 = r0 + sidx * per;
  int s1 = min(r1, s0 + per);
  float pool[27];
#pragma unroll
  for (int o = 0; o < 27; o++) pool[o] = 0.f;
  for (int tb = s0; tb < s1; tb += 64) {
    int nn = min(s1 - tb, 64);
    __syncthreads();
    for (int t = tid; t < nn * 27; t += 256) {
      int n = t / 27, j = t - n * 27;
      ushort2 va = aggh[(size_t)(tb + n) * XH + j];
      ushort2 vx = xt1h[(size_t)(tb + n) * XH + j];
      float* sr = scat + n * 109;
      sr[2 * j] = b2f(va.x);
      sr[2 * j + 1] = b2f(va.y);
      sr[54 + 2 * j] = b2f(vx.x);
      sr[54 + 2 * j + 1] = b2f(vx.y);
    }
    __syncthreads();
    if (lane < nn) {
      float acc[27];
#pragma unroll
      for (int o = 0; o < 27; o++) acc[o] = bl[obase + o];
      const float* rs = scat + lane * 109;
#pragma unroll 2
      for (int k = 0; k < 108; k++) {
        float v = rs[k];
        const float* wr = wcat + k * 108 + obase;
#pragma unroll
        for (int o = 0; o < 27; o++) acc[o] += v * wr[o];
      }
#pragma unroll
      for (int o = 0; o < 27; o++) pool[o] += fmaxf(acc[o], 0.f);
    }
  }
#pragma unroll
  for (int o = 0; o < 27; o++) {
#pragma unroll
    for (int off = 1; off < 64; off <<= 1) pool[o] += __shfl_xor(pool[o], off, 64);
  }
  if (lane == 0) {
    float* pb = pooled + b * DP2 + obase;
#pragma unroll
    for (int o = 0; o < 27; o++)
      if (pool[o] != 0.f) atomicAdd(&pb[o], pool[o]);
  }
}

// ---------- fused 2-layer head MLP: one block per batch, transposed (coalesced) weights ----------
template <int DIN, int DOUT>
__global__ void K256 k_headf(const float* __restrict__ X, int xstride,
                             const float* __restrict__ rs, const float* __restrict__ W1T,
                             const float* __restrict__ b1, const float* __restrict__ W2T,
                             const float* __restrict__ b2, float* __restrict__ Y,
                             int ystride, int ycol0) {
  __shared__ float sx[DIN];
  __shared__ float sh[256];
  int b = blockIdx.x, tid = threadIdx.x;
  float scale = rs ? rs[b] : 1.f;
  for (int f = tid; f < DIN; f += 256) sx[f] = X[(size_t)b * xstride + f] * scale;
  __syncthreads();
  float acc = b1[tid];
#pragma unroll 4
  for (int k = 0; k < DIN; k++) acc += sx[k] * W1T[k * 256 + tid];
  sh[tid] = fmaxf(acc, 0.f);
  __syncthreads();
  if (tid < DOUT) {
    float a = b2[tid];
#pragma unroll 4
    for (int k = 0; k < 256; k++) a += sh[k] * W2T[k * DOUT + tid];
    Y[(size_t)b * ystride + ycol0 + tid] = a;
  }
}

// ---------- weight-streaming FC: 64-out tile x NB-batch tile, X staged k-major in LDS ----------
// Thread = one output column x (NB/4) batches in registers; weight load coalesced, 1 load
// feeds NB/4 FMAs; LDS reads are wave-broadcast (all lanes same address).
template <int DIN, int DOUT, int NB, int KT, bool RELU>
__global__ void K256 k_fcws(const float* __restrict__ X, int xstride,
                            const float* __restrict__ WT, const float* __restrict__ bias,
                            float* __restrict__ Y, int ystride) {
  constexpr int BPT = NB / 4;
  constexpr int XP = NB + 4;  // pad to break staging bank conflicts
  __shared__ float xs[KT][XP];
  int ob = blockIdx.x * 64;
  int bb = blockIdx.y * NB;
  int tid = threadIdx.x;
  int otid = tid & 63;
  int b0 = (tid >> 6) * BPT;
  int o = ob + otid;
  float acc[BPT];
  float bv = bias[o];
#pragma unroll
  for (int i = 0; i < BPT; i++) acc[i] = bv;
  for (int kt = 0; kt < DIN; kt += KT) {
    __syncthreads();
    for (int idx = tid; idx < NB * KT; idx += 256) {
      int b = idx / KT, k = idx - b * KT;  // read coalesced in k
      xs[k][b] = X[(size_t)(bb + b) * xstride + kt + k];
    }
    __syncthreads();
#pragma unroll 2
    for (int k = 0; k < KT; k++) {
      float w = WT[(size_t)(kt + k) * DOUT + o];
#pragma unroll
      for (int i = 0; i < BPT; i++) acc[i] += xs[k][b0 + i] * w;
    }
  }
#pragma unroll
  for (int i = 0; i < BPT; i++) {
    float v = RELU ? fmaxf(acc[i], 0.f) : acc[i];
    Y[(size_t)(bb + b0 + i) * ystride + o] = v;
  }
}

// ---------- final 512 -> 1 GEMV ----------
__global__ void __launch_bounds__(64) k_gemv1(const float* __restrict__ t2,
                                              const float* __restrict__ W3,
                                              const float* __restrict__ b3,
                                              float* __restrict__ out) {
  int b = blockIdx.x, lane = threadIdx.x;
  float a = 0.f;
  const float* row = t2 + (size_t)b * 512;
#pragma unroll 2
  for (int k = lane; k < 512; k += 64) a += row[k] * W3[k];
#pragma unroll
  for (int off = 32; off > 0; off >>= 1) a += __shfl_down(a, off, 64);
  if (lane == 0) out[b] = a + b3[0];
}

__global__ void k_report(float* out, float v, int n) {
  int i = blockIdx.x * 256 + threadIdx.x;
  if (i < n) out[i] = v;
}

extern "C" void kernel_launch(void* const* d_in, const int* in_sizes, int n_in,
                              void* d_out, int out_size, void* d_ws, size_t ws_size,
                              hipStream_t stream) {
  (void)in_sizes; (void)n_in;
  const float* mol_x = (const float*)d_in[0];
  const int* m_ei = (const int*)d_in[1];
  const int* m_batch = (const int*)d_in[2];
  const float* pro_x = (const float*)d_in[3];
  const int* p_ei = (const int*)d_in[4];
  const int* p_batch = (const int*)d_in[5];
  const float* mol_W1 = (const float*)d_in[6];
  const float* mol_b1 = (const float*)d_in[7];
  const float* mol_W2 = (const float*)d_in[8];
  const float* mol_b2 = (const float*)d_in[9];
  const float* c1_Wl = (const float*)d_in[10];
  const float* c1_bl = (const float*)d_in[11];
  const float* c1_Wr = (const float*)d_in[12];
  const float* c2_Wl = (const float*)d_in[13];
  const float* c2_bl = (const float*)d_in[14];
  const float* c2_Wr = (const float*)d_in[15];
  const float* pro_W1 = (const float*)d_in[16];
  const float* pro_b1 = (const float*)d_in[17];
  const float* pro_W2 = (const float*)d_in[18];
  const float* pro_b2 = (const float*)d_in[19];
  const float* fc1_W = (const float*)d_in[20];
  const float* fc1_b = (const float*)d_in[21];
  const float* fc2_W = (const float*)d_in[22];
  const float* fc2_b = (const float*)d_in[23];
  const float* out_W = (const float*)d_in[24];
  const float* out_b = (const float*)d_in[25];
  float* out = (float*)d_out;
  char* ws = (char*)d_ws;

  const int* m_row = m_ei;       // dst
  const int* m_col = m_ei + EM;  // src
  const int* p_e0 = p_ei;        // src
  const int* p_e1 = p_ei + EP;   // dst

  auto al = [](size_t x) { return (x + 255) & ~(size_t)255; };

  size_t o = 0;
  size_t o_pdeg = o;   o += al((size_t)NP * 4);
  size_t o_pstart = o; o += al((size_t)NP * 4);
  size_t o_pcsr = o;   o += al((size_t)EP * 4);
  size_t o_aggh = o;   o += al((size_t)NP * XH * 4);  // also pro binned (25.6MB)
  size_t o_xt1h = o;   o += al((size_t)NP * XH * 4);
  size_t o_pxh = o;    o += al((size_t)NP * XH * 4);
  size_t pro_end = o;

  o = 0;
  size_t o_mdeg = o;   o += al((size_t)NM * 4);
  size_t o_mstart = o; o += al((size_t)NM * 4);
  size_t o_mcsr = o;   o += al((size_t)EM * 4);
  size_t o_mxh = o;    o += al((size_t)NM * MH * 4);
  size_t o_hAh = o;    o += al((size_t)NM * MH * 4);  // also mol binned (3.2MB)
  size_t o_hBh = o;    o += al((size_t)NM * MH * 4);
  size_t mol_end = o;

  size_t tail = al(pro_end > mol_end ? pro_end : mol_end);
  size_t o_poolM = tail; tail += al((size_t)B * DM * 4);
  size_t o_poolP = tail; tail += al((size_t)B * DP2 * 4);
  size_t o_mbs = tail;   tail += al((size_t)(B + 1) * 4);
  size_t o_pbs = tail;   tail += al((size_t)(B + 1) * 4);
  size_t o_w1c = tail;   tail += al((size_t)108 * 56 * 4);
  size_t o_bl1 = tail;   tail += al(56 * 4);
  size_t o_w2c = tail;   tail += al((size_t)108 * 108 * 4);
  size_t o_mbc = tail;   tail += al(512 * 4);
  size_t o_pbc = tail;   tail += al(512 * 4);
  size_t o_mbh = tail;   tail += al(512 * 4);
  size_t o_pbh = tail;   tail += al(512 * 4);
  size_t o_mbed = tail;  tail += al(513 * 4);
  size_t o_pbed = tail;  tail += al(513 * 4);
  // MLP machinery
  size_t o_mh1T = tail;  tail += al((size_t)DM * 256 * 4);
  size_t o_mh2T = tail;  tail += al((size_t)256 * 112 * 4);
  size_t o_ph1T = tail;  tail += al((size_t)DP2 * 256 * 4);
  size_t o_ph2T = tail;  tail += al((size_t)256 * 144 * 4);
  size_t o_fc1T = tail;  tail += al((size_t)256 * 1024 * 4);
  size_t o_fc2T = tail;  tail += al((size_t)1024 * 512 * 4);
  size_t o_xc = tail;    tail += al((size_t)B * 256 * 4);
  size_t o_t1 = tail;    tail += al((size_t)B * 1024 * 4);
  size_t o_t2 = tail;    tail += al((size_t)B * 512 * 4);
  size_t o_invM = tail;  tail += al(B * 4);
  size_t o_invP = tail;  tail += al(B * 4);

  if (ws_size < tail) {
    k_report<<<1, 256, 0, stream>>>(out, (float)(ws_size >> 20), out_size);
    return;
  }

  int* mdeg = (int*)(ws + o_mdeg);
  int* mstart = (int*)(ws + o_mstart);
  int* mcsr = (int*)(ws + o_mcsr);
  ushort2* mxh = (ushort2*)(ws + o_mxh);
  ushort2* hAh = (ushort2*)(ws + o_hAh);
  ushort2* hBh = (ushort2*)(ws + o_hBh);
  int* pdeg = (int*)(ws + o_pdeg);
  int* pstart = (int*)(ws + o_pstart);
  int* pcsr = (int*)(ws + o_pcsr);
  ushort2* aggh = (ushort2*)(ws + o_aggh);
  ushort2* xt1h = (ushort2*)(ws + o_xt1h);
  ushort2* pxh = (ushort2*)(ws + o_pxh);
  float* poolM = (float*)(ws + o_poolM);
  float* poolP = (float*)(ws + o_poolP);
  int* mbs = (int*)(ws + o_mbs);
  int* pbs = (int*)(ws + o_pbs);
  float* w1cat = (float*)(ws + o_w1c);
  float* bl1c = (float*)(ws + o_bl1);
  float* w2cat = (float*)(ws + o_w2c);
  int* mbc = (int*)(ws + o_mbc);
  int* pbc = (int*)(ws + o_pbc);
  int* mbh = (int*)(ws + o_mbh);
  int* pbh = (int*)(ws + o_pbh);
  int* mbed = (int*)(ws + o_mbed);
  int* pbed = (int*)(ws + o_pbed);
  float* mh1T = (float*)(ws + o_mh1T);
  float* mh2T = (float*)(ws + o_mh2T);
  float* ph1T = (float*)(ws + o_ph1T);
  float* ph2T = (float*)(ws + o_ph2T);
  float* fc1T = (float*)(ws + o_fc1T);
  float* fc2T = (float*)(ws + o_fc2T);
  float* xc = (float*)(ws + o_xc);
  float* t1 = (float*)(ws + o_t1);
  float* t2 = (float*)(ws + o_t2);
  float* invM = (float*)(ws + o_invM);
  float* invP = (float*)(ws + o_invP);
  int2* mbinned = (int2*)hAh;   // consumed by k_build before hAh written
  int2* pbinned = (int2*)aggh;  // consumed by k_build before aggh written

  // weight prep
  k_prepw<<<(108 * 108 + 255) / 256, 256, 0, stream>>>(c1_Wl, c1_Wr, c1_bl, c2_Wl, c2_Wr,
                                                       w1cat, bl1c, w2cat);
  {
    auto tg = [](int R, int C) { return dim3((C + 31) / 32, (R + 31) / 32); };
    k_transT<<<tg(256, DM), 256, 0, stream>>>(mol_W1, mh1T, 256, DM);
    k_transT<<<tg(112, 256), 256, 0, stream>>>(mol_W2, mh2T, 112, 256);
    k_transT<<<tg(256, DP2), 256, 0, stream>>>(pro_W1, ph1T, 256, DP2);
    k_transT<<<tg(144, 256), 256, 0, stream>>>(pro_W2, ph2T, 144, 256);
    k_transT<<<tg(1024, 256), 256, 0, stream>>>(fc1_W, fc1T, 1024, 256);
    k_transT<<<tg(512, 1024), 256, 0, stream>>>(fc2_W, fc2T, 512, 1024);
  }

  // ===== MOL branch (bf16 rows; APPNP sums accumulate in f32, stored bf16/hop) =====
  constexpr int SHM = 8;
  constexpr int NBM = (NM + (1 << SHM) - 1) >> SHM;
  hipMemsetAsync(mbh, 0, 512 * 4, stream);
  hipMemsetAsync(poolM, 0, (size_t)B * DM * 4, stream);
  k_bhist<SHM><<<(EM + 4095) / 4096, 256, 0, stream>>>(m_row, mbh, EM);
  k_scanb<<<1, 512, 0, stream>>>(mbh, mbed, mbc, NBM, EM);
  k_bin<SHM><<<(EM + 4095) / 4096, 256, 0, stream>>>(m_col, m_row, mbc, mbinned, EM);
  k_build<SHM><<<NBM, 256, 0, stream>>>(mbinned, mbed, mdeg, mstart, mcsr, NM);
  k_bstart<<<(NM + 255) / 256, 256, 0, stream>>>(m_batch, mbs, NM);
  k_inv<<<1, 128, 0, stream>>>(mbs, invM);
  k_castg<39, MH><<<(NM * 39 + 255) / 256, 256, 0, stream>>>(mol_x, DM, mxh, NM);

  int gb_m = (NM * 64 + 255) / 256;
  k_pool_segh<8><<<B * 8, 256, 0, stream>>>(mxh, mbs, poolM, 0.05f);
  k_gatherm<<<gb_m, 256, 0, stream>>>(mxh, mstart, mdeg, mcsr, hAh, NM);
  k_pool_segh<8><<<B * 8, 256, 0, stream>>>(hAh, mbs, poolM, 0.2375f);
  k_gatherm<<<gb_m, 256, 0, stream>>>(hAh, mstart, mdeg, mcsr, hBh, NM);
  k_pool_segh<8><<<B * 8, 256, 0, stream>>>(hBh, mbs, poolM, 0.2375f);
  k_gatherm<<<gb_m, 256, 0, stream>>>(hBh, mstart, mdeg, mcsr, hAh, NM);
  k_pool_segh<8><<<B * 8, 256, 0, stream>>>(hAh, mbs, poolM, 0.2375f);
  k_gatherm<<<gb_m, 256, 0, stream>>>(hAh, mstart, mdeg, mcsr, hBh, NM);
  k_pool_segh<8><<<B * 8, 256, 0, stream>>>(hBh, mbs, poolM, 0.2375f);
  k_headf<DM, 112><<<B, 256, 0, stream>>>(poolM, DM, invM, mh1T, mol_b1, mh2T, mol_b2, xc,
                                          256, 0);

  // ===== PRO branch (bf16 rows) =====
  constexpr int SHP = 9;
  constexpr int NBP = (NP + (1 << SHP) - 1) >> SHP;
  hipMemsetAsync(pbh, 0, 512 * 4, stream);
  hipMemsetAsync(poolP, 0, (size_t)B * DP2 * 4, stream);
  k_bhist<SHP><<<(EP + 4095) / 4096, 256, 0, stream>>>(p_e1, pbh, EP);
  k_scanb<<<1, 512, 0, stream>>>(pbh, pbed, pbc, NBP, EP);
  k_bin<SHP><<<(EP + 4095) / 4096, 256, 0, stream>>>(p_e0, p_e1, pbc, pbinned, EP);
  k_build<SHP><<<NBP, 256, 0, stream>>>(pbinned, pbed, pdeg, pstart, pcsr, NP);
  k_bstart<<<(NP + 255) / 256, 256, 0, stream>>>(p_batch, pbs, NP);
  k_inv<<<1, 128, 0, stream>>>(pbs, invP);
  k_castg<27, XH><<<(NP * 27 + 255) / 256, 256, 0, stream>>>(pro_x, DPK, pxh, NP);

  int gb_p = (NP * 64 + 255) / 256;
  k_gatherh<<<gb_p, 256, 0, stream>>>((const ushort4*)pxh, pstart, pdeg, pcsr,
                                      (ushort4*)aggh, NP);
  k_sage1c<<<(NP + 63) / 64, 256, 0, stream>>>(pro_x, aggh, w1cat, bl1c, xt1h, NP);
  k_gatherh<<<gb_p, 256, 0, stream>>>((const ushort4*)xt1h, pstart, pdeg, pcsr,
                                      (ushort4*)aggh, NP);
  k_sage2c<8><<<B * 8, 256, 0, stream>>>(xt1h, aggh, w2cat, c2_bl, pbs, poolP);
  k_headf<DP2, 144><<<B, 256, 0, stream>>>(poolP, DP2, invP, ph1T, pro_b1, ph2T, pro_b2, xc,
                                           256, 112);

  // ===== final MLP: weight-streaming tiled FCs + GEMV =====
  {
    dim3 gA(1024 / 64, B / 32);  // 16 x 4 = 64 blocks
    k_fcws<256, 1024, 32, 128, true><<<gA, 256, 0, stream>>>(xc, 256, fc1T, fc1_b, t1, 1024);
    dim3 gB(512 / 64, B / 16);  // 8 x 8 = 64 blocks
    k_fcws<1024, 512, 16, 128, true><<<gB, 256, 0, stream>>>(t1, 1024, fc2T, fc2_b, t2, 512);
    k_gemv1<<<B, 64, 0, stream>>>(t2, out_W, out_b, out);
  }
}

// Round 16
// 774.124 us; speedup vs baseline: 1.1995x; 1.1995x over previous
//
#include <hip/hip_runtime.h>

#define K256 __launch_bounds__(256)

constexpr int B = 128;
constexpr int NM = 100000, EM = 400000;
constexpr int NP = 200000, EP = 3200000;
constexpr int DM = 78, DPK = 54, DP2 = 108;
constexpr int XH = 32;   // pro bf16 row stride in ushort2 (128 B)
constexpr int XH4 = 16;  // pro row stride in ushort4
constexpr int MH = 48;   // mol bf16 row stride in ushort2 (192 B, 3 lines)

// ---- bf16 helpers (RTNE) ----
__device__ __forceinline__ float b2f(unsigned short u) {
  return __uint_as_float((unsigned int)u << 16);
}
__device__ __forceinline__ unsigned short f2b(float f) {
  unsigned int b = __float_as_uint(f);
  return (unsigned short)((b + 0x7fffu + ((b >> 16) & 1u)) >> 16);
}

// ---------- CSR build: bucket histogram (LDS-aggregated, no per-node atomics) ----------
template <int SH>
__global__ void K256 k_bhist(const int* __restrict__ dst, int* __restrict__ bhist, int E) {
  __shared__ int lh[512];
  int tid = threadIdx.x;
  for (int t = tid; t < 512; t += 256) lh[t] = 0;
  __syncthreads();
  int c0 = blockIdx.x * 4096;
#pragma unroll
  for (int k = 0; k < 16; k++) {
    int e = c0 + k * 256 + tid;
    if (e < E) atomicAdd(&lh[dst[e] >> SH], 1);
  }
  __syncthreads();
  for (int t = tid; t < 512; t += 256) {
    int c = lh[t];
    if (c) atomicAdd(&bhist[t], c);
  }
}

// one-block scan of bucket counts -> bed (exclusive, +total) and bcur
__global__ void k_scanb(const int* __restrict__ bhist, int* __restrict__ bed,
                        int* __restrict__ bcur, int NB, int E) {
  __shared__ int s[512];
  int tid = threadIdx.x;
  int v = (tid < NB) ? bhist[tid] : 0;
  s[tid] = v;
  __syncthreads();
  for (int off = 1; off < 512; off <<= 1) {
    int t = (tid >= off) ? s[tid - off] : 0;
    __syncthreads();
    s[tid] += t;
    __syncthreads();
  }
  int excl = s[tid] - v;
  if (tid < NB) {
    bed[tid] = excl;
    bcur[tid] = excl;
  }
  if (tid == NB - 1) bed[NB] = E;
}

// Pass A: bucket-grouped edge binning (counting-sort per 4096-edge chunk).
template <int SH>
__global__ void K256 k_bin(const int* __restrict__ src, const int* __restrict__ dst,
                           int* __restrict__ bcur, int2* __restrict__ binned, int E) {
  __shared__ int lh[512];
  __shared__ int gbase[512];
  int c0 = blockIdx.x * 4096;
  int tid = threadIdx.x;
  for (int t = tid; t < 512; t += 256) lh[t] = 0;
  __syncthreads();
  int r[16], dcache[16];
#pragma unroll
  for (int k = 0; k < 16; k++) {
    int e = c0 + k * 256 + tid;
    if (e < E) {
      int d = dst[e];
      dcache[k] = d;
      r[k] = atomicAdd(&lh[d >> SH], 1);
    }
  }
  __syncthreads();
  for (int b = tid; b < 512; b += 256) {
    int c = lh[b];
    gbase[b] = c ? atomicAdd(&bcur[b], c) : 0;
  }
  __syncthreads();
#pragma unroll
  for (int k = 0; k < 16; k++) {
    int e = c0 + k * 256 + tid;
    if (e < E) {
      int d = dcache[k];
      binned[gbase[d >> SH] + r[k]] = make_int2(src[e], d);
    }
  }
}

// Pass B (fused): per-bucket count -> LDS scan -> deg/starts write -> CSR fill.
template <int SH>
__global__ void K256 k_build(const int2* __restrict__ binned, const int* __restrict__ bed,
                             int* __restrict__ deg, int* __restrict__ starts,
                             int* __restrict__ csr, int N) {
  constexpr int NN = 1 << SH;
  constexpr int P = NN / 256;
  __shared__ int lcnt[NN];
  __shared__ int lpair[256];
  int b = blockIdx.x, base = b << SH, tid = threadIdx.x;
  int nn = min(N - base, NN);
  for (int t = tid; t < NN; t += 256) lcnt[t] = 0;
  __syncthreads();
  int e0 = bed[b], e1 = bed[b + 1];
  for (int e = e0 + tid; e < e1; e += 256) atomicAdd(&lcnt[binned[e].y - base], 1);
  __syncthreads();
  int loc[P];
  int psum = 0;
#pragma unroll
  for (int p = 0; p < P; p++) {
    loc[p] = lcnt[tid * P + p];
    psum += loc[p];
  }
  lpair[tid] = psum;
  __syncthreads();
  for (int off = 1; off < 256; off <<= 1) {
    int t = (tid >= off) ? lpair[tid - off] : 0;
    __syncthreads();
    lpair[tid] += t;
    __syncthreads();
  }
  int run = lpair[tid] - psum;
  __syncthreads();  // done reading lcnt as counts; reuse as cursors
#pragma unroll
  for (int p = 0; p < P; p++) {
    int i = tid * P + p;
    int st = e0 + run;
    if (i < nn) {
      deg[base + i] = loc[p];
      starts[base + i] = st;
    }
    lcnt[i] = st;
    run += loc[p];
  }
  __syncthreads();
  for (int e = e0 + tid; e < e1; e += 256) {
    int2 sd = binned[e];
    int p = atomicAdd(&lcnt[sd.y - base], 1);
    csr[p] = sd.x;
  }
}

// ---------- batch segment starts (batch is sorted) ----------
__global__ void K256 k_bstart(const int* __restrict__ batch, int* __restrict__ bstart, int N) {
  int i = blockIdx.x * 256 + threadIdx.x;
  if (i < N) {
    int b = batch[i];
    int pb = (i == 0) ? -1 : batch[i - 1];
    for (int bb = pb + 1; bb <= b; bb++) bstart[bb] = i;
    if (i == N - 1)
      for (int bb = b + 1; bb <= B; bb++) bstart[bb] = N;
  }
}

__global__ void k_inv(const int* __restrict__ bstart, float* __restrict__ inv) {
  int b = threadIdx.x;
  if (b < B) inv[b] = 1.f / fmaxf((float)(bstart[b + 1] - bstart[b]), 1.f);
}

// ---------- tiled transpose ----------
__global__ void K256 k_transT(const float* __restrict__ in, float* __restrict__ out, int R,
                              int C) {
  __shared__ float t[32][33];
  int cb = blockIdx.x * 32, rb = blockIdx.y * 32;
  int tx = threadIdx.x & 31, ty = threadIdx.x >> 5;
  for (int i = ty; i < 32; i += 8) {
    int r = rb + i, c = cb + tx;
    if (r < R && c < C) t[i][tx] = in[(size_t)r * C + c];
  }
  __syncthreads();
  for (int i = ty; i < 32; i += 8) {
    int c = cb + i, r = rb + tx;
    if (r < R && c < C) out[(size_t)c * R + r] = t[tx][i];
  }
}

// ---------- weight prep: cat-form transposed weights ----------
__global__ void K256 k_prepw(const float* __restrict__ c1Wl, const float* __restrict__ c1Wr,
                             const float* __restrict__ c1bl, const float* __restrict__ c2Wl,
                             const float* __restrict__ c2Wr, float* __restrict__ w1cat,
                             float* __restrict__ bl1c, float* __restrict__ w2cat) {
  int i = blockIdx.x * 256 + threadIdx.x;
  if (i < 108 * 56) {
    int k = i / 56, o = i - k * 56;
    w1cat[i] = (o < 54) ? ((k < 54) ? c1Wl[o * 54 + k] : c1Wr[o * 54 + (k - 54)]) : 0.f;
  }
  if (i < 108 * 108) {
    int k = i / 108, o = i - k * 108;
    w2cat[i] = (k < 54) ? c2Wl[o * 54 + k] : c2Wr[o * 54 + (k - 54)];
  }
  if (i < 56) bl1c[i] = (i < 54) ? c1bl[i] : 0.f;
}

// ---------- cast f32 rows -> bf16 rows ----------
template <int DF2, int XHD>
__global__ void K256 k_castg(const float* __restrict__ x, int sstride,
                             ushort2* __restrict__ xh, int N) {
  int t = blockIdx.x * 256 + threadIdx.x;
  if (t < N * DF2) {
    int n = t / DF2, j = t - n * DF2;
    float2 v = *(const float2*)(x + (size_t)n * sstride + 2 * j);
    xh[(size_t)n * XHD + j] = make_ushort2(f2b(v.x), f2b(v.y));
  }
}

// ---------- pro bf16 gather: 4 edges/wave, ushort4 lanes (14 of 16), 8-deep ILP ----------
__global__ void K256 k_gatherh(const ushort4* __restrict__ xh4, const int* __restrict__ starts,
                               const int* __restrict__ deg, const int* __restrict__ csr,
                               ushort4* __restrict__ outh4, int N) {
  int wid = (blockIdx.x * 256 + threadIdx.x) >> 6;
  int lane = threadIdx.x & 63;
  if (wid >= N) return;
  int s = starts[wid], d = deg[wid];
  const int* cp = csr + s;
  int quarter = lane >> 4, sl = lane & 15;
  bool act = sl < 14;
  float a0 = 0.f, a1 = 0.f, a2 = 0.f, a3 = 0.f;
  float b0 = 0.f, b1 = 0.f, b2 = 0.f, b3 = 0.f;
  int j = 0;
  for (; j + 8 <= d; j += 8) {
    if (act) {
      ushort4 v = xh4[(size_t)cp[j + quarter] * XH4 + sl];
      ushort4 w = xh4[(size_t)cp[j + 4 + quarter] * XH4 + sl];
      a0 += b2f(v.x);
      a1 += b2f(v.y);
      a2 += b2f(v.z);
      a3 += b2f(v.w);
      b0 += b2f(w.x);
      b1 += b2f(w.y);
      b2 += b2f(w.z);
      b3 += b2f(w.w);
    }
  }
  for (; j + 4 <= d; j += 4) {
    if (act) {
      ushort4 v = xh4[(size_t)cp[j + quarter] * XH4 + sl];
      a0 += b2f(v.x);
      a1 += b2f(v.y);
      a2 += b2f(v.z);
      a3 += b2f(v.w);
    }
  }
  int r = d - j;
  if (quarter < r && act) {
    ushort4 v = xh4[(size_t)cp[j + quarter] * XH4 + sl];
    a0 += b2f(v.x);
    a1 += b2f(v.y);
    a2 += b2f(v.z);
    a3 += b2f(v.w);
  }
  a0 += b0;
  a1 += b1;
  a2 += b2;
  a3 += b3;
  a0 += __shfl_xor(a0, 16, 64);
  a1 += __shfl_xor(a1, 16, 64);
  a2 += __shfl_xor(a2, 16, 64);
  a3 += __shfl_xor(a3, 16, 64);
  a0 += __shfl_xor(a0, 32, 64);
  a1 += __shfl_xor(a1, 32, 64);
  a2 += __shfl_xor(a2, 32, 64);
  a3 += __shfl_xor(a3, 32, 64);
  if (lane < 14) {
    float inv = 1.f / fmaxf((float)d, 1.f);
    outh4[(size_t)wid * XH4 + lane] =
        make_ushort4(f2b(a0 * inv), f2b(a1 * inv), f2b(a2 * inv), f2b(a3 * inv));
  }
}

// ---------- mol bf16 gather (sum): wave per node, 39 ushort2 lanes, 4-deep ILP ----------
__global__ void K256 k_gatherm(const ushort2* __restrict__ xh, const int* __restrict__ starts,
                               const int* __restrict__ deg, const int* __restrict__ csr,
                               ushort2* __restrict__ outh, int N) {
  int wid = (blockIdx.x * 256 + threadIdx.x) >> 6;
  int lane = threadIdx.x & 63;
  if (wid >= N) return;
  int s = starts[wid], d = deg[wid];
  const int* cp = csr + s;
  bool act = lane < 39;
  float ax = 0.f, ay = 0.f, bx = 0.f, by = 0.f;
  int j = 0;
  for (; j + 4 <= d; j += 4) {
    if (act) {
      ushort2 v0 = xh[(size_t)cp[j] * MH + lane];
      ushort2 v1 = xh[(size_t)cp[j + 1] * MH + lane];
      ushort2 v2 = xh[(size_t)cp[j + 2] * MH + lane];
      ushort2 v3 = xh[(size_t)cp[j + 3] * MH + lane];
      ax += b2f(v0.x) + b2f(v2.x);
      ay += b2f(v0.y) + b2f(v2.y);
      bx += b2f(v1.x) + b2f(v3.x);
      by += b2f(v1.y) + b2f(v3.y);
    }
  }
  for (; j < d; j++) {
    if (act) {
      ushort2 v = xh[(size_t)cp[j] * MH + lane];
      ax += b2f(v.x);
      ay += b2f(v.y);
    }
  }
  ax += bx;
  ay += by;
  if (act) outh[(size_t)wid * MH + lane] = make_ushort2(f2b(ax), f2b(ay));
}

// ---------- mol segmented pooling over bf16 rows, split + ILP-4 ----------
template <int SPLIT>
__global__ void K256 k_pool_segh(const ushort2* __restrict__ xh, const int* __restrict__ bstart,
                                 float* __restrict__ pooled, float coef) {
  constexpr int NPB = 6;  // 39 u2 * 6 = 234 threads
  __shared__ float sp[NPB * DM];
  int b = blockIdx.x / SPLIT;
  int sidx = blockIdx.x - b * SPLIT;
  int tid = threadIdx.x;
  int r0 = bstart[b], r1 = bstart[b + 1];
  int len = r1 - r0;
  int per = (len + SPLIT - 1) / SPLIT;
  int s0 = r0 + sidx * per;
  int s1 = min(r1, s0 + per);
  if (tid < 39 * NPB) {
    int ioff = tid / 39, j = tid - ioff * 39;
    float a0x = 0.f, a0y = 0.f, a1x = 0.f, a1y = 0.f;
    int i = s0 + ioff;
    for (; i + 3 * NPB < s1; i += 4 * NPB) {
      ushort2 v0 = xh[(size_t)i * MH + j];
      ushort2 v1 = xh[(size_t)(i + NPB) * MH + j];
      ushort2 v2 = xh[(size_t)(i + 2 * NPB) * MH + j];
      ushort2 v3 = xh[(size_t)(i + 3 * NPB) * MH + j];
      a0x += b2f(v0.x) + b2f(v2.x);
      a0y += b2f(v0.y) + b2f(v2.y);
      a1x += b2f(v1.x) + b2f(v3.x);
      a1y += b2f(v1.y) + b2f(v3.y);
    }
    for (; i < s1; i += NPB) {
      ushort2 v = xh[(size_t)i * MH + j];
      a0x += b2f(v.x);
      a0y += b2f(v.y);
    }
    sp[ioff * DM + 2 * j] = a0x + a1x;
    sp[ioff * DM + 2 * j + 1] = a0y + a1y;
  }
  __syncthreads();
  if (tid < DM) {
    float s = 0.f;
#pragma unroll
    for (int g = 0; g < NPB; g++) s += sp[g * DM + tid];
    s *= coef;
    if (s != 0.f) atomicAdd(&pooled[b * DM + tid], s);
  }
}

// ---------- SAGE conv1 cat-form: 64-node tile, 4 waves x 14 outputs; bf16 agg in, bf16 out ----------
__global__ void __launch_bounds__(256, 4) k_sage1c(
    const float* __restrict__ x, const ushort2* __restrict__ aggh,
    const float* __restrict__ wcat, const float* __restrict__ blc,
    ushort2* __restrict__ outh, int N) {
  __shared__ float scat[64 * 109];
  int base = blockIdx.x * 64;
  int nn = min(N - base, 64);
  int tid = threadIdx.x;
  for (int t = tid; t < nn * 27; t += 256) {
    int n = t / 27, j = t - n * 27;
    ushort2 va = aggh[(size_t)(base + n) * XH + j];
    float2 vx = *(const float2*)(x + (size_t)(base + n) * 54 + 2 * j);
    float* sr = scat + n * 109;
    sr[2 * j] = b2f(va.x);
    sr[2 * j + 1] = b2f(va.y);
    sr[54 + 2 * j] = vx.x;
    sr[54 + 2 * j + 1] = vx.y;
  }
  __syncthreads();
  int w = tid >> 6, lane = tid & 63;
  int obase = __builtin_amdgcn_readfirstlane(w * 14);
  if (lane >= nn) return;
  float acc[14];
#pragma unroll
  for (int o = 0; o < 14; o++) acc[o] = blc[obase + o];
  const float* rs = scat + lane * 109;
#pragma unroll 2
  for (int k = 0; k < 108; k++) {
    float v = rs[k];
    const float* wr = wcat + k * 56 + obase;
#pragma unroll
    for (int o = 0; o < 14; o++) acc[o] += v * wr[o];
  }
  ushort2* op = outh + (size_t)(base + lane) * XH + (obase >> 1);
#pragma unroll
  for (int o = 0; o < 7; o++)
    op[o] = make_ushort2(f2b(fmaxf(acc[2 * o], 0.f)), f2b(fmaxf(acc[2 * o + 1], 0.f)));
}

// ---------- conv2 + pool cat-form: 64-node tile, 4 waves x 27 outputs; bf16 inputs ----------
template <int SPLIT>
__global__ void __launch_bounds__(256, 4) k_sage2c(
    const ushort2* __restrict__ xt1h, const ushort2* __restrict__ aggh,
    const float* __restrict__ wcat, const float* __restrict__ bl,
    const int* __restrict__ bstart, float* __restrict__ pooled) {
  __shared__ float scat[64 * 109];
  int b = blockIdx.x / SPLIT;
  int sidx = blockIdx.x - b * SPLIT;
  int tid = threadIdx.x;
  int w = tid >> 6, lane = tid & 63;
  int obase = __builtin_amdgcn_readfirstlane(w * 27);
  int r0 = bstart[b], r1 = bstart[b + 1];
  int len = r1 - r0;
  int per = (len + SPLIT - 1) / SPLIT;
  int s0 = r0 + sidx * per;
  int s1 = min(r1, s0 + per);
  float pool[27];
#pragma unroll
  for (int o = 0; o < 27; o++) pool[o] = 0.f;
  for (int tb = s0; tb < s1; tb += 64) {
    int nn = min(s1 - tb, 64);
    __syncthreads();
    for (int t = tid; t < nn * 27; t += 256) {
      int n = t / 27, j = t - n * 27;
      ushort2 va = aggh[(size_t)(tb + n) * XH + j];
      ushort2 vx = xt1h[(size_t)(tb + n) * XH + j];
      float* sr = scat + n * 109;
      sr[2 * j] = b2f(va.x);
      sr[2 * j + 1] = b2f(va.y);
      sr[54 + 2 * j] = b2f(vx.x);
      sr[54 + 2 * j + 1] = b2f(vx.y);
    }
    __syncthreads();
    if (lane < nn) {
      float acc[27];
#pragma unroll
      for (int o = 0; o < 27; o++) acc[o] = bl[obase + o];
      const float* rs = scat + lane * 109;
#pragma unroll 2
      for (int k = 0; k < 108; k++) {
        float v = rs[k];
        const float* wr = wcat + k * 108 + obase;
#pragma unroll
        for (int o = 0; o < 27; o++) acc[o] += v * wr[o];
      }
#pragma unroll
      for (int o = 0; o < 27; o++) pool[o] += fmaxf(acc[o], 0.f);
    }
  }
#pragma unroll
  for (int o = 0; o < 27; o++) {
#pragma unroll
    for (int off = 1; off < 64; off <<= 1) pool[o] += __shfl_xor(pool[o], off, 64);
  }
  if (lane == 0) {
    float* pb = pooled + b * DP2 + obase;
#pragma unroll
    for (int o = 0; o < 27; o++)
      if (pool[o] != 0.f) atomicAdd(&pb[o], pool[o]);
  }
}

// ---------- fused 2-layer head MLP: one block per batch, transposed (coalesced) weights ----------
template <int DIN, int DOUT>
__global__ void K256 k_headf(const float* __restrict__ X, int xstride,
                             const float* __restrict__ rs, const float* __restrict__ W1T,
                             const float* __restrict__ b1, const float* __restrict__ W2T,
                             const float* __restrict__ b2, float* __restrict__ Y,
                             int ystride, int ycol0) {
  __shared__ float sx[DIN];
  __shared__ float sh[256];
  int b = blockIdx.x, tid = threadIdx.x;
  float scale = rs ? rs[b] : 1.f;
  for (int f = tid; f < DIN; f += 256) sx[f] = X[(size_t)b * xstride + f] * scale;
  __syncthreads();
  float acc = b1[tid];
#pragma unroll 4
  for (int k = 0; k < DIN; k++) acc += sx[k] * W1T[k * 256 + tid];
  sh[tid] = fmaxf(acc, 0.f);
  __syncthreads();
  if (tid < DOUT) {
    float a = b2[tid];
#pragma unroll 4
    for (int k = 0; k < 256; k++) a += sh[k] * W2T[k * DOUT + tid];
    Y[(size_t)b * ystride + ycol0 + tid] = a;
  }
}

// ---------- mini-GEMM FC: both operands staged in LDS (bulk-parallel weight stream) ----------
// Grid (DOUT/64, B/NB). Thread = output col (otid) x BPT batches (wave picks batch slice).
// Inner loop: LDS-only (xw conflict-free by lane, xs wave-broadcast). Output = X@WT + bias
// (no activation; consumer applies relu).
template <int DIN, int DOUT, int NB, int KT, bool RELUIN>
__global__ void K256 k_fcg(const float* __restrict__ X, int xstride,
                           const float* __restrict__ WT, const float* __restrict__ bias,
                           float* __restrict__ Y, int ystride) {
  constexpr int BPT = NB / 4;
  __shared__ float xw[KT][64];
  __shared__ float xs[NB][KT + 1];
  int ob = blockIdx.x * 64;
  int bb = blockIdx.y * NB;
  int tid = threadIdx.x;
  int otid = tid & 63;
  int b0 = (tid >> 6) * BPT;
  int o = ob + otid;
  float acc[BPT];
#pragma unroll
  for (int i = 0; i < BPT; i++) acc[i] = 0.f;
  for (int kt = 0; kt < DIN; kt += KT) {
    __syncthreads();
    for (int idx = tid; idx < NB * KT; idx += 256) {
      int b = idx / KT, k = idx - b * KT;  // consecutive tid -> consecutive k: coalesced+conflict-free
      float v = X[(size_t)(bb + b) * xstride + kt + k];
      if (RELUIN) v = fmaxf(v, 0.f);
      xs[b][k] = v;
    }
    for (int idx = tid; idx < KT * 64; idx += 256) {
      int k = idx >> 6, oo = idx & 63;  // coalesced 64-float rows
      xw[k][oo] = WT[(size_t)(kt + k) * DOUT + ob + oo];
    }
    __syncthreads();
#pragma unroll 4
    for (int k = 0; k < KT; k++) {
      float wv = xw[k][otid];
#pragma unroll
      for (int i = 0; i < BPT; i++) acc[i] += xs[b0 + i][k] * wv;
    }
  }
  float bv = bias[o];
#pragma unroll
  for (int i = 0; i < BPT; i++) Y[(size_t)(bb + b0 + i) * ystride + o] = acc[i] + bv;
}

// ---------- final 512 -> 1 GEMV (applies relu to its input) ----------
__global__ void __launch_bounds__(64) k_gemv1(const float* __restrict__ t2,
                                              const float* __restrict__ W3,
                                              const float* __restrict__ b3,
                                              float* __restrict__ out) {
  int b = blockIdx.x, lane = threadIdx.x;
  float a = 0.f;
  const float* row = t2 + (size_t)b * 512;
#pragma unroll 2
  for (int k = lane; k < 512; k += 64) a += fmaxf(row[k], 0.f) * W3[k];
#pragma unroll
  for (int off = 32; off > 0; off >>= 1) a += __shfl_down(a, off, 64);
  if (lane == 0) out[b] = a + b3[0];
}

__global__ void k_report(float* out, float v, int n) {
  int i = blockIdx.x * 256 + threadIdx.x;
  if (i < n) out[i] = v;
}

extern "C" void kernel_launch(void* const* d_in, const int* in_sizes, int n_in,
                              void* d_out, int out_size, void* d_ws, size_t ws_size,
                              hipStream_t stream) {
  (void)in_sizes; (void)n_in;
  const float* mol_x = (const float*)d_in[0];
  const int* m_ei = (const int*)d_in[1];
  const int* m_batch = (const int*)d_in[2];
  const float* pro_x = (const float*)d_in[3];
  const int* p_ei = (const int*)d_in[4];
  const int* p_batch = (const int*)d_in[5];
  const float* mol_W1 = (const float*)d_in[6];
  const float* mol_b1 = (const float*)d_in[7];
  const float* mol_W2 = (const float*)d_in[8];
  const float* mol_b2 = (const float*)d_in[9];
  const float* c1_Wl = (const float*)d_in[10];
  const float* c1_bl = (const float*)d_in[11];
  const float* c1_Wr = (const float*)d_in[12];
  const float* c2_Wl = (const float*)d_in[13];
  const float* c2_bl = (const float*)d_in[14];
  const float* c2_Wr = (const float*)d_in[15];
  const float* pro_W1 = (const float*)d_in[16];
  const float* pro_b1 = (const float*)d_in[17];
  const float* pro_W2 = (const float*)d_in[18];
  const float* pro_b2 = (const float*)d_in[19];
  const float* fc1_W = (const float*)d_in[20];
  const float* fc1_b = (const float*)d_in[21];
  const float* fc2_W = (const float*)d_in[22];
  const float* fc2_b = (const float*)d_in[23];
  const float* out_W = (const float*)d_in[24];
  const float* out_b = (const float*)d_in[25];
  float* out = (float*)d_out;
  char* ws = (char*)d_ws;

  const int* m_row = m_ei;       // dst
  const int* m_col = m_ei + EM;  // src
  const int* p_e0 = p_ei;        // src
  const int* p_e1 = p_ei + EP;   // dst

  auto al = [](size_t x) { return (x + 255) & ~(size_t)255; };

  size_t o = 0;
  size_t o_pdeg = o;   o += al((size_t)NP * 4);
  size_t o_pstart = o; o += al((size_t)NP * 4);
  size_t o_pcsr = o;   o += al((size_t)EP * 4);
  size_t o_aggh = o;   o += al((size_t)NP * XH * 4);  // also pro binned (25.6MB)
  size_t o_xt1h = o;   o += al((size_t)NP * XH * 4);
  size_t o_pxh = o;    o += al((size_t)NP * XH * 4);
  size_t pro_end = o;

  o = 0;
  size_t o_mdeg = o;   o += al((size_t)NM * 4);
  size_t o_mstart = o; o += al((size_t)NM * 4);
  size_t o_mcsr = o;   o += al((size_t)EM * 4);
  size_t o_mxh = o;    o += al((size_t)NM * MH * 4);
  size_t o_hAh = o;    o += al((size_t)NM * MH * 4);  // also mol binned (3.2MB)
  size_t o_hBh = o;    o += al((size_t)NM * MH * 4);
  size_t mol_end = o;

  size_t tail = al(pro_end > mol_end ? pro_end : mol_end);
  size_t o_poolM = tail; tail += al((size_t)B * DM * 4);
  size_t o_poolP = tail; tail += al((size_t)B * DP2 * 4);
  size_t o_mbs = tail;   tail += al((size_t)(B + 1) * 4);
  size_t o_pbs = tail;   tail += al((size_t)(B + 1) * 4);
  size_t o_w1c = tail;   tail += al((size_t)108 * 56 * 4);
  size_t o_bl1 = tail;   tail += al(56 * 4);
  size_t o_w2c = tail;   tail += al((size_t)108 * 108 * 4);
  size_t o_mbc = tail;   tail += al(512 * 4);
  size_t o_pbc = tail;   tail += al(512 * 4);
  size_t o_mbh = tail;   tail += al(512 * 4);
  size_t o_pbh = tail;   tail += al(512 * 4);
  size_t o_mbed = tail;  tail += al(513 * 4);
  size_t o_pbed = tail;  tail += al(513 * 4);
  // MLP machinery
  size_t o_mh1T = tail;  tail += al((size_t)DM * 256 * 4);
  size_t o_mh2T = tail;  tail += al((size_t)256 * 112 * 4);
  size_t o_ph1T = tail;  tail += al((size_t)DP2 * 256 * 4);
  size_t o_ph2T = tail;  tail += al((size_t)256 * 144 * 4);
  size_t o_fc1T = tail;  tail += al((size_t)256 * 1024 * 4);
  size_t o_fc2T = tail;  tail += al((size_t)1024 * 512 * 4);
  size_t o_xc = tail;    tail += al((size_t)B * 256 * 4);
  size_t o_t1 = tail;    tail += al((size_t)B * 1024 * 4);
  size_t o_t2 = tail;    tail += al((size_t)B * 512 * 4);
  size_t o_invM = tail;  tail += al(B * 4);
  size_t o_invP = tail;  tail += al(B * 4);

  if (ws_size < tail) {
    k_report<<<1, 256, 0, stream>>>(out, (float)(ws_size >> 20), out_size);
    return;
  }

  int* mdeg = (int*)(ws + o_mdeg);
  int* mstart = (int*)(ws + o_mstart);
  int* mcsr = (int*)(ws + o_mcsr);
  ushort2* mxh = (ushort2*)(ws + o_mxh);
  ushort2* hAh = (ushort2*)(ws + o_hAh);
  ushort2* hBh = (ushort2*)(ws + o_hBh);
  int* pdeg = (int*)(ws + o_pdeg);
  int* pstart = (int*)(ws + o_pstart);
  int* pcsr = (int*)(ws + o_pcsr);
  ushort2* aggh = (ushort2*)(ws + o_aggh);
  ushort2* xt1h = (ushort2*)(ws + o_xt1h);
  ushort2* pxh = (ushort2*)(ws + o_pxh);
  float* poolM = (float*)(ws + o_poolM);
  float* poolP = (float*)(ws + o_poolP);
  int* mbs = (int*)(ws + o_mbs);
  int* pbs = (int*)(ws + o_pbs);
  float* w1cat = (float*)(ws + o_w1c);
  float* bl1c = (float*)(ws + o_bl1);
  float* w2cat = (float*)(ws + o_w2c);
  int* mbc = (int*)(ws + o_mbc);
  int* pbc = (int*)(ws + o_pbc);
  int* mbh = (int*)(ws + o_mbh);
  int* pbh = (int*)(ws + o_pbh);
  int* mbed = (int*)(ws + o_mbed);
  int* pbed = (int*)(ws + o_pbed);
  float* mh1T = (float*)(ws + o_mh1T);
  float* mh2T = (float*)(ws + o_mh2T);
  float* ph1T = (float*)(ws + o_ph1T);
  float* ph2T = (float*)(ws + o_ph2T);
  float* fc1T = (float*)(ws + o_fc1T);
  float* fc2T = (float*)(ws + o_fc2T);
  float* xc = (float*)(ws + o_xc);
  float* t1 = (float*)(ws + o_t1);
  float* t2 = (float*)(ws + o_t2);
  float* invM = (float*)(ws + o_invM);
  float* invP = (float*)(ws + o_invP);
  int2* mbinned = (int2*)hAh;   // consumed by k_build before hAh written
  int2* pbinned = (int2*)aggh;  // consumed by k_build before aggh written

  // weight prep
  k_prepw<<<(108 * 108 + 255) / 256, 256, 0, stream>>>(c1_Wl, c1_Wr, c1_bl, c2_Wl, c2_Wr,
                                                       w1cat, bl1c, w2cat);
  {
    auto tg = [](int R, int C) { return dim3((C + 31) / 32, (R + 31) / 32); };
    k_transT<<<tg(256, DM), 256, 0, stream>>>(mol_W1, mh1T, 256, DM);
    k_transT<<<tg(112, 256), 256, 0, stream>>>(mol_W2, mh2T, 112, 256);
    k_transT<<<tg(256, DP2), 256, 0, stream>>>(pro_W1, ph1T, 256, DP2);
    k_transT<<<tg(144, 256), 256, 0, stream>>>(pro_W2, ph2T, 144, 256);
    k_transT<<<tg(1024, 256), 256, 0, stream>>>(fc1_W, fc1T, 1024, 256);
    k_transT<<<tg(512, 1024), 256, 0, stream>>>(fc2_W, fc2T, 512, 1024);
  }

  // ===== MOL branch (bf16 rows; APPNP sums accumulate in f32, stored bf16/hop) =====
  constexpr int SHM = 8;
  constexpr int NBM = (NM + (1 << SHM) - 1) >> SHM;
  hipMemsetAsync(mbh, 0, 512 * 4, stream);
  hipMemsetAsync(poolM, 0, (size_t)B * DM * 4, stream);
  k_bhist<SHM><<<(EM + 4095) / 4096, 256, 0, stream>>>(m_row, mbh, EM);
  k_scanb<<<1, 512, 0, stream>>>(mbh, mbed, mbc, NBM, EM);
  k_bin<SHM><<<(EM + 4095) / 4096, 256, 0, stream>>>(m_col, m_row, mbc, mbinned, EM);
  k_build<SHM><<<NBM, 256, 0, stream>>>(mbinned, mbed, mdeg, mstart, mcsr, NM);
  k_bstart<<<(NM + 255) / 256, 256, 0, stream>>>(m_batch, mbs, NM);
  k_inv<<<1, 128, 0, stream>>>(mbs, invM);
  k_castg<39, MH><<<(NM * 39 + 255) / 256, 256, 0, stream>>>(mol_x, DM, mxh, NM);

  int gb_m = (NM * 64 + 255) / 256;
  k_pool_segh<8><<<B * 8, 256, 0, stream>>>(mxh, mbs, poolM, 0.05f);
  k_gatherm<<<gb_m, 256, 0, stream>>>(mxh, mstart, mdeg, mcsr, hAh, NM);
  k_pool_segh<8><<<B * 8, 256, 0, stream>>>(hAh, mbs, poolM, 0.2375f);
  k_gatherm<<<gb_m, 256, 0, stream>>>(hAh, mstart, mdeg, mcsr, hBh, NM);
  k_pool_segh<8><<<B * 8, 256, 0, stream>>>(hBh, mbs, poolM, 0.2375f);
  k_gatherm<<<gb_m, 256, 0, stream>>>(hBh, mstart, mdeg, mcsr, hAh, NM);
  k_pool_segh<8><<<B * 8, 256, 0, stream>>>(hAh, mbs, poolM, 0.2375f);
  k_gatherm<<<gb_m, 256, 0, stream>>>(hAh, mstart, mdeg, mcsr, hBh, NM);
  k_pool_segh<8><<<B * 8, 256, 0, stream>>>(hBh, mbs, poolM, 0.2375f);
  k_headf<DM, 112><<<B, 256, 0, stream>>>(poolM, DM, invM, mh1T, mol_b1, mh2T, mol_b2, xc,
                                          256, 0);

  // ===== PRO branch (bf16 rows) =====
  constexpr int SHP = 9;
  constexpr int NBP = (NP + (1 << SHP) - 1) >> SHP;
  hipMemsetAsync(pbh, 0, 512 * 4, stream);
  hipMemsetAsync(poolP, 0, (size_t)B * DP2 * 4, stream);
  k_bhist<SHP><<<(EP + 4095) / 4096, 256, 0, stream>>>(p_e1, pbh, EP);
  k_scanb<<<1, 512, 0, stream>>>(pbh, pbed, pbc, NBP, EP);
  k_bin<SHP><<<(EP + 4095) / 4096, 256, 0, stream>>>(p_e0, p_e1, pbc, pbinned, EP);
  k_build<SHP><<<NBP, 256, 0, stream>>>(pbinned, pbed, pdeg, pstart, pcsr, NP);
  k_bstart<<<(NP + 255) / 256, 256, 0, stream>>>(p_batch, pbs, NP);
  k_inv<<<1, 128, 0, stream>>>(pbs, invP);
  k_castg<27, XH><<<(NP * 27 + 255) / 256, 256, 0, stream>>>(pro_x, DPK, pxh, NP);

  int gb_p = (NP * 64 + 255) / 256;
  k_gatherh<<<gb_p, 256, 0, stream>>>((const ushort4*)pxh, pstart, pdeg, pcsr,
                                      (ushort4*)aggh, NP);
  k_sage1c<<<(NP + 63) / 64, 256, 0, stream>>>(pro_x, aggh, w1cat, bl1c, xt1h, NP);
  k_gatherh<<<gb_p, 256, 0, stream>>>((const ushort4*)xt1h, pstart, pdeg, pcsr,
                                      (ushort4*)aggh, NP);
  k_sage2c<8><<<B * 8, 256, 0, stream>>>(xt1h, aggh, w2cat, c2_bl, pbs, poolP);
  k_headf<DP2, 144><<<B, 256, 0, stream>>>(poolP, DP2, invP, ph1T, pro_b1, ph2T, pro_b2, xc,
                                           256, 112);

  // ===== final MLP: mini-GEMM FCs (both operands LDS-staged) + GEMV =====
  {
    dim3 gA(1024 / 64, B / 8);  // 16 x 16 = 256 blocks
    k_fcg<256, 1024, 8, 128, false><<<gA, 256, 0, stream>>>(xc, 256, fc1T, fc1_b, t1, 1024);
    dim3 gB(512 / 64, B / 4);  // 8 x 32 = 256 blocks
    k_fcg<1024, 512, 4, 128, true><<<gB, 256, 0, stream>>>(t1, 1024, fc2T, fc2_b, t2, 512);
    k_gemv1<<<B, 64, 0, stream>>>(t2, out_W, out_b, out);
  }
}